// Round 14
// baseline (112.445 us; speedup 1.0000x reference)
//
#include <hip/hip_runtime.h>

#define N_CH 128
#define CAP 7680  // LDS packed-edge cache per bucket (30.7KB); expected max bucket ~4400

typedef short bf16x8 __attribute__((ext_vector_type(8)));
typedef float f32x4 __attribute__((ext_vector_type(4)));

__device__ __forceinline__ unsigned short f2bf(float f) {
    unsigned int u = __float_as_uint(f);
    unsigned int r = (u + 0x7fffu + ((u >> 16) & 1u)) >> 16;
    return (unsigned short)r;
}
__device__ __forceinline__ unsigned int pkbf(float a, float b) {
    return (unsigned int)f2bf(a) | ((unsigned int)f2bf(b) << 16);
}
__device__ __forceinline__ float bflo(unsigned int v) { return __uint_as_float(v << 16); }
__device__ __forceinline__ float bfhi(unsigned int v) { return __uint_as_float(v & 0xffff0000u); }

// ---- init: prep Bt1/Bt2 | per-1024-edge-block histogram (x-cast moved out) --------
__global__ __launch_bounds__(256) void k_inithist(const float* __restrict__ Ws1,
                                                  const float* __restrict__ Wn1,
                                                  const float* __restrict__ Ws2,
                                                  const float* __restrict__ Wn2,
                                                  unsigned short* __restrict__ Bt1,
                                                  unsigned short* __restrict__ Bt2,
                                                  const int* __restrict__ dst,
                                                  int* __restrict__ H, int e, int nbh,
                                                  int nbkt) {
    __shared__ int hist[256];
    int b = blockIdx.x, t = threadIdx.x;
    if (b < 192) {
        int idx = b * 256 + t;
        if (idx < 128 * 256) {
            int n = idx >> 8, k = idx & 255;
            float v = (k < 128) ? Ws1[k * 128 + n] : Wn1[(k - 128) * 128 + n];
            Bt1[idx] = f2bf(v);
        } else {
            int j = idx - 128 * 256;
            int n = j >> 7, k = j & 127;
            float v = (n < 64) ? Ws2[k * 64 + n] : Wn2[k * 64 + (n - 64)];
            Bt2[j] = f2bf(v);
        }
    } else {
        int hb = b - 192;
        hist[t] = 0;
        __syncthreads();
        int i = hb * 1024 + t * 4;
        if (i + 3 < e) {
            int4 d4 = *(const int4*)&dst[i];
            atomicAdd(&hist[d4.x >> 8], 1);
            atomicAdd(&hist[d4.y >> 8], 1);
            atomicAdd(&hist[d4.z >> 8], 1);
            atomicAdd(&hist[d4.w >> 8], 1);
        } else {
            for (int j = i; j < e && j < i + 4; ++j) atomicAdd(&hist[dst[j] >> 8], 1);
        }
        __syncthreads();
        if (t < nbkt) H[t * nbh + hb] = hist[t];
    }
}

// ---------------- CSR stage 1b: block sums of H ----------------
__global__ __launch_bounds__(256) void k_reduce(const int* __restrict__ H,
                                                int* __restrict__ bsum, int tot) {
    __shared__ int sm[256];
    int i = blockIdx.x * 256 + threadIdx.x;
    sm[threadIdx.x] = (i < tot) ? H[i] : 0;
    __syncthreads();
    for (int s = 128; s > 0; s >>= 1) {
        if (threadIdx.x < s) sm[threadIdx.x] += sm[threadIdx.x + s];
        __syncthreads();
    }
    if (threadIdx.x == 0) bsum[blockIdx.x] = sm[0];
}

// ---------------- CSR stage 1c: exclusive scan of H -> Hs ----------------
__global__ __launch_bounds__(256) void k_scan(const int* __restrict__ H,
                                              const int* __restrict__ bsum,
                                              int* __restrict__ Hs, int tot) {
    __shared__ int sm[256];
    __shared__ int sbase;
    int t = threadIdx.x, b = blockIdx.x;
    int acc = 0;
    for (int j = t; j < b; j += 256) acc += bsum[j];  // <=3 coalesced iters
    sm[t] = acc;
    __syncthreads();
    for (int s = 128; s > 0; s >>= 1) {
        if (t < s) sm[t] += sm[t + s];
        __syncthreads();
    }
    if (t == 0) sbase = sm[0];
    __syncthreads();
    int base = sbase;
    __syncthreads();
    int i = b * 256 + t;
    int v = (i < tot) ? H[i] : 0;
    sm[t] = v;
    __syncthreads();
    for (int off = 1; off < 256; off <<= 1) {
        int add = (t >= off) ? sm[t - off] : 0;
        __syncthreads();
        sm[t] += add;
        __syncthreads();
    }
    if (i < tot) Hs[i] = base + sm[t] - v;  // exclusive
}

// ---- CSR stage 2 ∥ x-cast: scatter packed edges (LDS cursors) + cast x -> bf16 ----
// Scatter blocks (latency/LDS-bound) co-schedule with cast blocks (HBM-bound).
// pack = (dst&255)<<16 | src  (src < 65536) — 4B per edge.
__global__ __launch_bounds__(256) void k_scatcast(const int* __restrict__ src,
                                                  const int* __restrict__ dst,
                                                  const int* __restrict__ Hs,
                                                  int* __restrict__ buf,
                                                  int e, int nbh, int nbkt,
                                                  const float* __restrict__ x,
                                                  uint4* __restrict__ xb4, int nxq) {
    __shared__ int cur[256];
    int t = threadIdx.x, b = blockIdx.x;
    if (b < nbh) {
        if (t < nbkt) cur[t] = Hs[t * nbh + b];
        __syncthreads();
        int i = b * 1024 + t * 4;
        if (i + 3 < e) {
            int4 d4 = *(const int4*)&dst[i];
            int4 s4 = *(const int4*)&src[i];
            int r0 = atomicAdd(&cur[d4.x >> 8], 1);
            buf[r0] = ((d4.x & 255) << 16) | s4.x;
            int r1 = atomicAdd(&cur[d4.y >> 8], 1);
            buf[r1] = ((d4.y & 255) << 16) | s4.y;
            int r2 = atomicAdd(&cur[d4.z >> 8], 1);
            buf[r2] = ((d4.z & 255) << 16) | s4.z;
            int r3 = atomicAdd(&cur[d4.w >> 8], 1);
            buf[r3] = ((d4.w & 255) << 16) | s4.w;
        } else {
            for (int j = i; j < e && j < i + 4; ++j) {
                int d = dst[j];
                int r = atomicAdd(&cur[d >> 8], 1);
                buf[r] = ((d & 255) << 16) | src[j];
            }
        }
    } else {
        int q = (b - nbh) * 256 + t;
        if (q < nxq) {
            const float4* xf = (const float4*)x;
            float4 f0 = xf[2 * q], f1 = xf[2 * q + 1];
            uint4 o;
            o.x = pkbf(f0.x, f0.y); o.y = pkbf(f0.z, f0.w);
            o.z = pkbf(f1.x, f1.y); o.w = pkbf(f1.z, f1.w);
            xb4[q] = o;  // node-major [N][16 uint4]
        }
    }
}

// ------ CSR stage 3: per-bucket LDS sort by low byte -> csr(u16)/deg/row_start -----
__global__ __launch_bounds__(256) void k_bucket(const int* __restrict__ buf,
                                                const int* __restrict__ Hs,
                                                unsigned short* __restrict__ csr_src,
                                                int* __restrict__ deg,
                                                int* __restrict__ row_start,
                                                int e, int nbh, int nbkt, int n) {
    __shared__ int hist[256];
    __shared__ int excl[256];
    __shared__ int cur[256];
    __shared__ int cache[CAP];
    int t = threadIdx.x, b = blockIdx.x;
    int base = Hs[b * nbh];
    int end = (b == nbkt - 1) ? e : Hs[(b + 1) * nbh];
    int cnt = end - base;
    hist[t] = 0;
    __syncthreads();
    for (int i = t; i < cnt; i += 256) {
        int v = buf[base + i];
        if (i < CAP) cache[i] = v;
        atomicAdd(&hist[(v >> 16) & 255], 1);
    }
    __syncthreads();
    int v = hist[t];
    excl[t] = v;
    __syncthreads();
    for (int off = 1; off < 256; off <<= 1) {
        int add = (t >= off) ? excl[t - off] : 0;
        __syncthreads();
        excl[t] += add;
        __syncthreads();
    }
    int ex = excl[t] - v;  // exclusive
    cur[t] = ex;
    int node = b * 256 + t;
    if (node < n) {
        deg[node] = v;
        row_start[node] = base + ex;
    }
    __syncthreads();
    for (int i = t; i < cnt; i += 256) {
        int ed = (i < CAP) ? cache[i] : buf[base + i];
        int r = atomicAdd(&cur[(ed >> 16) & 255], 1);  // LDS atomic
        csr_src[base + r] = (unsigned short)(ed & 0xFFFF);
    }
}

// ---------------- neighbor-mean of x (bf16): xagg = mean(xb[neigh]) ----------------
// one wave per node; 4 quarters of 16 lanes each gather a different neighbor row
// (16 lanes x uint4 = 256B row); 4-deep -> 16 rows in flight per wave.
__global__ __launch_bounds__(256) void k_aggx(const uint4* __restrict__ xb4,
                                              uint4* __restrict__ xagg4,
                                              const int* __restrict__ row_start,
                                              const int* __restrict__ deg,
                                              const unsigned short* __restrict__ csr, int n) {
    int gw = (blockIdx.x * 256 + threadIdx.x) >> 6;
    int lane = threadIdx.x & 63;
    if (gw >= n) return;
    int start = row_start[gw];
    int cnt = deg[gw];
    const int q = lane >> 4;
    const int cl = lane & 15;
    float a0 = 0.f, a1 = 0.f, a2 = 0.f, a3 = 0.f, a4 = 0.f, a5 = 0.f, a6 = 0.f, a7 = 0.f;
    int i = 0;
    for (; i + 16 <= cnt; i += 16) {
        int e0 = csr[start + i + q];
        int e1 = csr[start + i + 4 + q];
        int e2 = csr[start + i + 8 + q];
        int e3 = csr[start + i + 12 + q];
        uint4 v0 = xb4[e0 * 16 + cl];
        uint4 v1 = xb4[e1 * 16 + cl];
        uint4 v2 = xb4[e2 * 16 + cl];
        uint4 v3 = xb4[e3 * 16 + cl];
        a0 += bflo(v0.x) + bflo(v1.x) + bflo(v2.x) + bflo(v3.x);
        a1 += bfhi(v0.x) + bfhi(v1.x) + bfhi(v2.x) + bfhi(v3.x);
        a2 += bflo(v0.y) + bflo(v1.y) + bflo(v2.y) + bflo(v3.y);
        a3 += bfhi(v0.y) + bfhi(v1.y) + bfhi(v2.y) + bfhi(v3.y);
        a4 += bflo(v0.z) + bflo(v1.z) + bflo(v2.z) + bflo(v3.z);
        a5 += bfhi(v0.z) + bfhi(v1.z) + bfhi(v2.z) + bfhi(v3.z);
        a6 += bflo(v0.w) + bflo(v1.w) + bflo(v2.w) + bflo(v3.w);
        a7 += bfhi(v0.w) + bfhi(v1.w) + bfhi(v2.w) + bfhi(v3.w);
    }
    if (i + 8 <= cnt) {
        int e0 = csr[start + i + q];
        int e1 = csr[start + i + 4 + q];
        uint4 v0 = xb4[e0 * 16 + cl];
        uint4 v1 = xb4[e1 * 16 + cl];
        a0 += bflo(v0.x) + bflo(v1.x); a1 += bfhi(v0.x) + bfhi(v1.x);
        a2 += bflo(v0.y) + bflo(v1.y); a3 += bfhi(v0.y) + bfhi(v1.y);
        a4 += bflo(v0.z) + bflo(v1.z); a5 += bfhi(v0.z) + bfhi(v1.z);
        a6 += bflo(v0.w) + bflo(v1.w); a7 += bfhi(v0.w) + bfhi(v1.w);
        i += 8;
    }
    for (; i < cnt; i += 4) {
        int nbi = i + q;
        if (nbi < cnt) {
            uint4 va = xb4[csr[start + nbi] * 16 + cl];
            a0 += bflo(va.x); a1 += bfhi(va.x);
            a2 += bflo(va.y); a3 += bfhi(va.y);
            a4 += bflo(va.z); a5 += bfhi(va.z);
            a6 += bflo(va.w); a7 += bfhi(va.w);
        }
    }
    // combine the 4 quarters
    a0 += __shfl_xor(a0, 16); a0 += __shfl_xor(a0, 32);
    a1 += __shfl_xor(a1, 16); a1 += __shfl_xor(a1, 32);
    a2 += __shfl_xor(a2, 16); a2 += __shfl_xor(a2, 32);
    a3 += __shfl_xor(a3, 16); a3 += __shfl_xor(a3, 32);
    a4 += __shfl_xor(a4, 16); a4 += __shfl_xor(a4, 32);
    a5 += __shfl_xor(a5, 16); a5 += __shfl_xor(a5, 32);
    a6 += __shfl_xor(a6, 16); a6 += __shfl_xor(a6, 32);
    a7 += __shfl_xor(a7, 16); a7 += __shfl_xor(a7, 32);

    float inv = 1.0f / fmaxf((float)cnt, 1.0f);
    if (q == 0) {
        uint4 o;
        o.x = pkbf(inv * a0, inv * a1);
        o.y = pkbf(inv * a2, inv * a3);
        o.z = pkbf(inv * a4, inv * a5);
        o.w = pkbf(inv * a6, inv * a7);
        xagg4[gw * 16 + cl] = o;
    }
}

// ---- fused gemm12: h1 = relu([xb|xagg]@Bt1^T + b1) (LDS-local), [out|p2] = h1@Bt2^T + b2
__global__ __launch_bounds__(256) void k_gemm12(const uint4* __restrict__ xb4,
                                                const uint4* __restrict__ xagg4,
                                                const unsigned short* __restrict__ Bt1,
                                                const float* __restrict__ b1,
                                                const unsigned short* __restrict__ Bt2,
                                                const float* __restrict__ b2,
                                                float* __restrict__ out,
                                                unsigned short* __restrict__ p2, int M) {
    __shared__ unsigned short As[64][256];
    unsigned short* lds = &As[0][0];
    const int m0 = blockIdx.x * 64;
    const int tid = threadIdx.x;
    const int w = tid >> 6;
    const int l = tid & 63;
    const int fr = l & 15;
    const int kq = l >> 4;

    for (int p = tid; p < 2048; p += 256) {
        int row = p >> 5, c = p & 31;
        int gr = m0 + row;
        uint4 v = make_uint4(0, 0, 0, 0);
        if (gr < M) v = (c < 16) ? xb4[gr * 16 + c] : xagg4[gr * 16 + (c - 16)];
        *(uint4*)&As[row][(c ^ (row & 7)) * 8] = v;
    }
    __syncthreads();

    f32x4 acc[2][4] = {};
#pragma unroll
    for (int kt = 0; kt < 8; ++kt) {
        bf16x8 bfr[2];
#pragma unroll
        for (int ct = 0; ct < 2; ++ct) {
            int nn = w * 32 + ct * 16 + fr;
            bfr[ct] = *(const bf16x8*)&Bt1[nn * 256 + kt * 32 + kq * 8];
        }
        bf16x8 af[4];
#pragma unroll
        for (int rt = 0; rt < 4; ++rt) {
            int row = rt * 16 + fr;
            int c = (kt * 4 + kq) ^ (row & 7);
            af[rt] = *(bf16x8*)&As[row][c * 8];
        }
#pragma unroll
        for (int ct = 0; ct < 2; ++ct)
#pragma unroll
            for (int rt = 0; rt < 4; ++rt)
                acc[ct][rt] = __builtin_amdgcn_mfma_f32_16x16x32_bf16(af[rt], bfr[ct],
                                                                      acc[ct][rt], 0, 0, 0);
    }
    __syncthreads();  // all phase-A LDS reads complete before overwrite

#pragma unroll
    for (int ct = 0; ct < 2; ++ct) {
        int col = w * 32 + ct * 16 + fr;
        float bv = b1[col];
        int c8 = col >> 3, c7 = col & 7;
#pragma unroll
        for (int rt = 0; rt < 4; ++rt) {
#pragma unroll
            for (int j = 0; j < 4; ++j) {
                int row = rt * 16 + (l >> 4) * 4 + j;
                unsigned short hv = f2bf(fmaxf(acc[ct][rt][j] + bv, 0.f));
                lds[row * 128 + (c8 ^ (row & 7)) * 8 + c7] = hv;
            }
        }
    }
    __syncthreads();

    f32x4 acc2[2][4] = {};
#pragma unroll
    for (int kt = 0; kt < 4; ++kt) {
        bf16x8 bfr[2];
#pragma unroll
        for (int ct = 0; ct < 2; ++ct) {
            int nn = w * 32 + ct * 16 + fr;
            bfr[ct] = *(const bf16x8*)&Bt2[nn * 128 + kt * 32 + kq * 8];
        }
        bf16x8 af[4];
#pragma unroll
        for (int rt = 0; rt < 4; ++rt) {
            int row = rt * 16 + fr;
            int c = (kt * 4 + kq) ^ (row & 7);
            af[rt] = *(bf16x8*)&lds[row * 128 + c * 8];
        }
#pragma unroll
        for (int ct = 0; ct < 2; ++ct)
#pragma unroll
            for (int rt = 0; rt < 4; ++rt)
                acc2[ct][rt] = __builtin_amdgcn_mfma_f32_16x16x32_bf16(af[rt], bfr[ct],
                                                                       acc2[ct][rt], 0, 0, 0);
    }

#pragma unroll
    for (int ct = 0; ct < 2; ++ct) {
        int col = w * 32 + ct * 16 + fr;
        bool isS = col < 64;  // wave-uniform per 16-col tile
        float bv = isS ? b2[col] : 0.f;
#pragma unroll
        for (int rt = 0; rt < 4; ++rt) {
#pragma unroll
            for (int j = 0; j < 4; ++j) {
                int row = m0 + rt * 16 + (l >> 4) * 4 + j;
                if (row < M) {
                    float v = acc2[ct][rt][j];
                    if (isS) out[row * 64 + col] = v + bv;
                    else p2[row * 64 + (col - 64)] = f2bf(v);
                }
            }
        }
    }
}

// ---------------- layer-2 aggregation: out += mean_neigh(p2) (64 ch bf16) ----------
// 8 groups of 8 lanes; each group gathers one 128B row via uint4 (8 rows/instr).
__global__ __launch_bounds__(256) void k_agg2_add(const unsigned int* __restrict__ p,
                                                  float* __restrict__ out,
                                                  const int* __restrict__ row_start,
                                                  const int* __restrict__ deg,
                                                  const unsigned short* __restrict__ csr,
                                                  int n) {
    int gw = (blockIdx.x * 256 + threadIdx.x) >> 6;
    int lane = threadIdx.x & 63;
    if (gw >= n) return;
    int start = row_start[gw];
    int cnt = deg[gw];
    const int g = lane >> 3;
    const int cl = lane & 7;
    float a0 = 0.f, a1 = 0.f, a2 = 0.f, a3 = 0.f, a4 = 0.f, a5 = 0.f, a6 = 0.f, a7 = 0.f;
    int i = 0;
    for (; i + 16 <= cnt; i += 16) {
        int e0 = csr[start + i + g];
        int e1 = csr[start + i + 8 + g];
        uint4 v0 = *(const uint4*)&p[e0 * 32 + cl * 4];
        uint4 v1 = *(const uint4*)&p[e1 * 32 + cl * 4];
        a0 += bflo(v0.x) + bflo(v1.x); a1 += bfhi(v0.x) + bfhi(v1.x);
        a2 += bflo(v0.y) + bflo(v1.y); a3 += bfhi(v0.y) + bfhi(v1.y);
        a4 += bflo(v0.z) + bflo(v1.z); a5 += bfhi(v0.z) + bfhi(v1.z);
        a6 += bflo(v0.w) + bflo(v1.w); a7 += bfhi(v0.w) + bfhi(v1.w);
    }
    for (; i < cnt; i += 8) {
        int nbi = i + g;
        if (nbi < cnt) {
            int ia = csr[start + nbi];
            uint4 va = *(const uint4*)&p[ia * 32 + cl * 4];
            a0 += bflo(va.x); a1 += bfhi(va.x);
            a2 += bflo(va.y); a3 += bfhi(va.y);
            a4 += bflo(va.z); a5 += bfhi(va.z);
            a6 += bflo(va.w); a7 += bfhi(va.w);
        }
    }
    a0 += __shfl_xor(a0, 8); a0 += __shfl_xor(a0, 16); a0 += __shfl_xor(a0, 32);
    a1 += __shfl_xor(a1, 8); a1 += __shfl_xor(a1, 16); a1 += __shfl_xor(a1, 32);
    a2 += __shfl_xor(a2, 8); a2 += __shfl_xor(a2, 16); a2 += __shfl_xor(a2, 32);
    a3 += __shfl_xor(a3, 8); a3 += __shfl_xor(a3, 16); a3 += __shfl_xor(a3, 32);
    a4 += __shfl_xor(a4, 8); a4 += __shfl_xor(a4, 16); a4 += __shfl_xor(a4, 32);
    a5 += __shfl_xor(a5, 8); a5 += __shfl_xor(a5, 16); a5 += __shfl_xor(a5, 32);
    a6 += __shfl_xor(a6, 8); a6 += __shfl_xor(a6, 16); a6 += __shfl_xor(a6, 32);
    a7 += __shfl_xor(a7, 8); a7 += __shfl_xor(a7, 16); a7 += __shfl_xor(a7, 32);
    float inv = 1.0f / fmaxf((float)cnt, 1.0f);
    if (g == 0) {
        float4 oa = *(const float4*)&out[gw * 64 + cl * 8];
        float4 ob = *(const float4*)&out[gw * 64 + cl * 8 + 4];
        oa.x += inv * a0; oa.y += inv * a1; oa.z += inv * a2; oa.w += inv * a3;
        ob.x += inv * a4; ob.y += inv * a5; ob.z += inv * a6; ob.w += inv * a7;
        *(float4*)&out[gw * 64 + cl * 8] = oa;
        *(float4*)&out[gw * 64 + cl * 8 + 4] = ob;
    }
}

extern "C" void kernel_launch(void* const* d_in, const int* in_sizes, int n_in,
                              void* d_out, int out_size, void* d_ws, size_t ws_size,
                              hipStream_t stream) {
    const float* x   = (const float*)d_in[0];
    const int*   src = (const int*)d_in[1];
    const int*   dst = (const int*)d_in[2];
    const float* Ws1 = (const float*)d_in[3];
    const float* Wn1 = (const float*)d_in[4];
    const float* b1  = (const float*)d_in[5];
    const float* Ws2 = (const float*)d_in[6];
    const float* Wn2 = (const float*)d_in[7];
    const float* b2  = (const float*)d_in[8];
    float* out = (float*)d_out;
    const int N = in_sizes[0] / N_CH;  // 50000
    const int E = in_sizes[1];         // 800000

    const int nbh  = (E + 1023) / 1024;    // 782 hist/scatter blocks (1024 edges each)
    const int nbkt = (N + 255) / 256;      // 196 buckets (dst>>8)
    const int htot = nbkt * nbh;           // 153272 table entries
    const int nb2  = (htot + 255) / 256;   // 599 scan blocks
    const int nxq  = N * 16;               // 800000 uint4 cast items
    const int nxb  = (nxq + 255) / 256;    // 3125

    // workspace layout (256B-aligned); ws_size ~268MB, ample
    char* ws = (char*)d_ws;
    int* deg       = (int*)(ws + 0);           // N
    int* row_start = (int*)(ws + 200704);      // N
    int* bsum2     = (int*)(ws + 401408);      // nb2 -> 403968
    unsigned short* csr_src = (unsigned short*)(ws + 403968);  // E u16 -> 2003968
    int* H         = (int*)(ws + 2003968);     // htot -> 2617344
    int* Hs        = (int*)(ws + 2617344);     // htot -> 3230720
    int* buf       = (int*)(ws + 3230720);     // E packed -> 6430720
    unsigned short* xb   = (unsigned short*)(ws + 6430720);   // bf16 [N][128]
    unsigned short* xagg = (unsigned short*)(ws + 19230720);  // bf16 [N][128]
    unsigned short* p2   = (unsigned short*)(ws + 32030720);  // bf16 [N][64]
    unsigned short* Bt1  = (unsigned short*)(ws + 38430720);  // 64KB
    unsigned short* Bt2  = (unsigned short*)(ws + 38496256);  // 32KB

    k_inithist<<<192 + nbh, 256, 0, stream>>>(Ws1, Wn1, Ws2, Wn2, Bt1, Bt2, dst, H, E, nbh,
                                              nbkt);
    k_reduce<<<nb2, 256, 0, stream>>>(H, bsum2, htot);
    k_scan<<<nb2, 256, 0, stream>>>(H, bsum2, Hs, htot);
    k_scatcast<<<nbh + nxb, 256, 0, stream>>>(src, dst, Hs, buf, E, nbh, nbkt, x, (uint4*)xb,
                                              nxq);
    k_bucket<<<nbkt, 256, 0, stream>>>(buf, Hs, csr_src, deg, row_start, E, nbh, nbkt, N);

    k_aggx<<<(N + 3) / 4, 256, 0, stream>>>((const uint4*)xb, (uint4*)xagg, row_start, deg,
                                            csr_src, N);

    const int gb = (N + 63) / 64;  // 782
    k_gemm12<<<gb, 256, 0, stream>>>((const uint4*)xb, (const uint4*)xagg, Bt1, b1, Bt2, b2,
                                     out, p2, N);
    k_agg2_add<<<(N + 3) / 4, 256, 0, stream>>>((const unsigned int*)p2, out, row_start, deg,
                                                csr_src, N);
}

// Round 15
// 111.311 us; speedup vs baseline: 1.0102x; 1.0102x over previous
//
#include <hip/hip_runtime.h>

#define N_CH 128
#define CAP 7680  // LDS packed-edge cache per bucket (30.7KB); expected max bucket ~4400

typedef short bf16x8 __attribute__((ext_vector_type(8)));
typedef float f32x4 __attribute__((ext_vector_type(4)));

__device__ __forceinline__ unsigned short f2bf(float f) {
    unsigned int u = __float_as_uint(f);
    unsigned int r = (u + 0x7fffu + ((u >> 16) & 1u)) >> 16;
    return (unsigned short)r;
}
__device__ __forceinline__ unsigned int pkbf(float a, float b) {
    return (unsigned int)f2bf(a) | ((unsigned int)f2bf(b) << 16);
}
__device__ __forceinline__ float bflo(unsigned int v) { return __uint_as_float(v << 16); }
__device__ __forceinline__ float bfhi(unsigned int v) { return __uint_as_float(v & 0xffff0000u); }

// ---------------- CSR stage 1a: pure per-1024-edge-block histogram (dst>>8) --------
__global__ __launch_bounds__(256) void k_hist(const int* __restrict__ dst,
                                              int* __restrict__ H, int e, int nbh,
                                              int nbkt) {
    __shared__ int hist[256];
    int t = threadIdx.x, hb = blockIdx.x;
    hist[t] = 0;
    __syncthreads();
    int i = hb * 1024 + t * 4;
    if (i + 3 < e) {
        int4 d4 = *(const int4*)&dst[i];
        atomicAdd(&hist[d4.x >> 8], 1);
        atomicAdd(&hist[d4.y >> 8], 1);
        atomicAdd(&hist[d4.z >> 8], 1);
        atomicAdd(&hist[d4.w >> 8], 1);
    } else {
        for (int j = i; j < e && j < i + 4; ++j) atomicAdd(&hist[dst[j] >> 8], 1);
    }
    __syncthreads();
    if (t < nbkt) H[t * nbh + hb] = hist[t];
}

// ---------------- CSR stage 1b: block sums of H ----------------
__global__ __launch_bounds__(256) void k_reduce(const int* __restrict__ H,
                                                int* __restrict__ bsum, int tot) {
    __shared__ int sm[256];
    int i = blockIdx.x * 256 + threadIdx.x;
    sm[threadIdx.x] = (i < tot) ? H[i] : 0;
    __syncthreads();
    for (int s = 128; s > 0; s >>= 1) {
        if (threadIdx.x < s) sm[threadIdx.x] += sm[threadIdx.x + s];
        __syncthreads();
    }
    if (threadIdx.x == 0) bsum[blockIdx.x] = sm[0];
}

// ---------------- CSR stage 1c: exclusive scan of H -> Hs ----------------
__global__ __launch_bounds__(256) void k_scan(const int* __restrict__ H,
                                              const int* __restrict__ bsum,
                                              int* __restrict__ Hs, int tot) {
    __shared__ int sm[256];
    __shared__ int sbase;
    int t = threadIdx.x, b = blockIdx.x;
    int acc = 0;
    for (int j = t; j < b; j += 256) acc += bsum[j];  // <=3 coalesced iters
    sm[t] = acc;
    __syncthreads();
    for (int s = 128; s > 0; s >>= 1) {
        if (t < s) sm[t] += sm[t + s];
        __syncthreads();
    }
    if (t == 0) sbase = sm[0];
    __syncthreads();
    int base = sbase;
    __syncthreads();
    int i = b * 256 + t;
    int v = (i < tot) ? H[i] : 0;
    sm[t] = v;
    __syncthreads();
    for (int off = 1; off < 256; off <<= 1) {
        int add = (t >= off) ? sm[t - off] : 0;
        __syncthreads();
        sm[t] += add;
        __syncthreads();
    }
    if (i < tot) Hs[i] = base + sm[t] - v;  // exclusive
}

// ---------------- CSR stage 2: pure scatter of packed edges (LDS cursors) ----------
// pack = (dst&255)<<16 | src  (src < 65536) — 4B per edge.
__global__ __launch_bounds__(256) void k_scatter(const int* __restrict__ src,
                                                 const int* __restrict__ dst,
                                                 const int* __restrict__ Hs,
                                                 int* __restrict__ buf,
                                                 int e, int nbh, int nbkt) {
    __shared__ int cur[256];
    int t = threadIdx.x, b = blockIdx.x;
    if (t < nbkt) cur[t] = Hs[t * nbh + b];
    __syncthreads();
    int i = b * 1024 + t * 4;
    if (i + 3 < e) {
        int4 d4 = *(const int4*)&dst[i];
        int4 s4 = *(const int4*)&src[i];
        int r0 = atomicAdd(&cur[d4.x >> 8], 1);
        buf[r0] = ((d4.x & 255) << 16) | s4.x;
        int r1 = atomicAdd(&cur[d4.y >> 8], 1);
        buf[r1] = ((d4.y & 255) << 16) | s4.y;
        int r2 = atomicAdd(&cur[d4.z >> 8], 1);
        buf[r2] = ((d4.z & 255) << 16) | s4.z;
        int r3 = atomicAdd(&cur[d4.w >> 8], 1);
        buf[r3] = ((d4.w & 255) << 16) | s4.w;
    } else {
        for (int j = i; j < e && j < i + 4; ++j) {
            int d = dst[j];
            int r = atomicAdd(&cur[d >> 8], 1);
            buf[r] = ((d & 255) << 16) | src[j];
        }
    }
}

// ---- CSR stage 3 ∥ x-cast ∥ weight-prep: bucket uses 196 blocks (<256 CUs), so the
// HBM-bound cast (3125 blocks) and weight-prep (192) fill the otherwise-idle CUs.
__global__ __launch_bounds__(256) void k_bucketcastw(const int* __restrict__ buf,
                                                     const int* __restrict__ Hs,
                                                     unsigned short* __restrict__ csr_src,
                                                     int* __restrict__ deg,
                                                     int* __restrict__ row_start,
                                                     int e, int nbh, int nbkt, int n,
                                                     const float* __restrict__ x,
                                                     uint4* __restrict__ xb4, int nxq,
                                                     const float* __restrict__ Ws1,
                                                     const float* __restrict__ Wn1,
                                                     const float* __restrict__ Ws2,
                                                     const float* __restrict__ Wn2,
                                                     unsigned short* __restrict__ Bt1,
                                                     unsigned short* __restrict__ Bt2) {
    __shared__ int hist[256];
    __shared__ int excl[256];
    __shared__ int cur[256];
    __shared__ int cache[CAP];
    int t = threadIdx.x, b = blockIdx.x;
    if (b < nbkt) {
        // ---- bucket: LDS sort by low byte -> csr(u16)/deg/row_start ----
        int base = Hs[b * nbh];
        int end = (b == nbkt - 1) ? e : Hs[(b + 1) * nbh];
        int cnt = end - base;
        hist[t] = 0;
        __syncthreads();
        for (int i = t; i < cnt; i += 256) {
            int v = buf[base + i];
            if (i < CAP) cache[i] = v;
            atomicAdd(&hist[(v >> 16) & 255], 1);
        }
        __syncthreads();
        int v = hist[t];
        excl[t] = v;
        __syncthreads();
        for (int off = 1; off < 256; off <<= 1) {
            int add = (t >= off) ? excl[t - off] : 0;
            __syncthreads();
            excl[t] += add;
            __syncthreads();
        }
        int ex = excl[t] - v;  // exclusive
        cur[t] = ex;
        int node = b * 256 + t;
        if (node < n) {
            deg[node] = v;
            row_start[node] = base + ex;
        }
        __syncthreads();
        for (int i = t; i < cnt; i += 256) {
            int ed = (i < CAP) ? cache[i] : buf[base + i];
            int r = atomicAdd(&cur[(ed >> 16) & 255], 1);  // LDS atomic
            csr_src[base + r] = (unsigned short)(ed & 0xFFFF);
        }
    } else if (b < nbkt + 192) {
        // ---- weight prep: Bt1 [128 n][256 k], Bt2 [128 n][128 k] ----
        int idx = (b - nbkt) * 256 + t;
        if (idx < 128 * 256) {
            int nn = idx >> 8, k = idx & 255;
            float v = (k < 128) ? Ws1[k * 128 + nn] : Wn1[(k - 128) * 128 + nn];
            Bt1[idx] = f2bf(v);
        } else {
            int j = idx - 128 * 256;
            int nn = j >> 7, k = j & 127;
            float v = (nn < 64) ? Ws2[k * 64 + nn] : Wn2[k * 64 + (nn - 64)];
            Bt2[j] = f2bf(v);
        }
    } else {
        // ---- cast x -> bf16 node-major [N][16 uint4] ----
        int q = (b - nbkt - 192) * 256 + t;
        if (q < nxq) {
            const float4* xf = (const float4*)x;
            float4 f0 = xf[2 * q], f1 = xf[2 * q + 1];
            uint4 o;
            o.x = pkbf(f0.x, f0.y); o.y = pkbf(f0.z, f0.w);
            o.z = pkbf(f1.x, f1.y); o.w = pkbf(f1.z, f1.w);
            xb4[q] = o;
        }
    }
}

// ---------------- neighbor-mean of x (bf16): xagg = mean(xb[neigh]) ----------------
// one wave per node; 4 quarters of 16 lanes each gather a different neighbor row
// (16 lanes x uint4 = 256B row); 4-deep -> 16 rows in flight per wave.
__global__ __launch_bounds__(256) void k_aggx(const uint4* __restrict__ xb4,
                                              uint4* __restrict__ xagg4,
                                              const int* __restrict__ row_start,
                                              const int* __restrict__ deg,
                                              const unsigned short* __restrict__ csr, int n) {
    int gw = (blockIdx.x * 256 + threadIdx.x) >> 6;
    int lane = threadIdx.x & 63;
    if (gw >= n) return;
    int start = row_start[gw];
    int cnt = deg[gw];
    const int q = lane >> 4;
    const int cl = lane & 15;
    float a0 = 0.f, a1 = 0.f, a2 = 0.f, a3 = 0.f, a4 = 0.f, a5 = 0.f, a6 = 0.f, a7 = 0.f;
    int i = 0;
    for (; i + 16 <= cnt; i += 16) {
        int e0 = csr[start + i + q];
        int e1 = csr[start + i + 4 + q];
        int e2 = csr[start + i + 8 + q];
        int e3 = csr[start + i + 12 + q];
        uint4 v0 = xb4[e0 * 16 + cl];
        uint4 v1 = xb4[e1 * 16 + cl];
        uint4 v2 = xb4[e2 * 16 + cl];
        uint4 v3 = xb4[e3 * 16 + cl];
        a0 += bflo(v0.x) + bflo(v1.x) + bflo(v2.x) + bflo(v3.x);
        a1 += bfhi(v0.x) + bfhi(v1.x) + bfhi(v2.x) + bfhi(v3.x);
        a2 += bflo(v0.y) + bflo(v1.y) + bflo(v2.y) + bflo(v3.y);
        a3 += bfhi(v0.y) + bfhi(v1.y) + bfhi(v2.y) + bfhi(v3.y);
        a4 += bflo(v0.z) + bflo(v1.z) + bflo(v2.z) + bflo(v3.z);
        a5 += bfhi(v0.z) + bfhi(v1.z) + bfhi(v2.z) + bfhi(v3.z);
        a6 += bflo(v0.w) + bflo(v1.w) + bflo(v2.w) + bflo(v3.w);
        a7 += bfhi(v0.w) + bfhi(v1.w) + bfhi(v2.w) + bfhi(v3.w);
    }
    if (i + 8 <= cnt) {
        int e0 = csr[start + i + q];
        int e1 = csr[start + i + 4 + q];
        uint4 v0 = xb4[e0 * 16 + cl];
        uint4 v1 = xb4[e1 * 16 + cl];
        a0 += bflo(v0.x) + bflo(v1.x); a1 += bfhi(v0.x) + bfhi(v1.x);
        a2 += bflo(v0.y) + bflo(v1.y); a3 += bfhi(v0.y) + bfhi(v1.y);
        a4 += bflo(v0.z) + bflo(v1.z); a5 += bfhi(v0.z) + bfhi(v1.z);
        a6 += bflo(v0.w) + bflo(v1.w); a7 += bfhi(v0.w) + bfhi(v1.w);
        i += 8;
    }
    for (; i < cnt; i += 4) {
        int nbi = i + q;
        if (nbi < cnt) {
            uint4 va = xb4[csr[start + nbi] * 16 + cl];
            a0 += bflo(va.x); a1 += bfhi(va.x);
            a2 += bflo(va.y); a3 += bfhi(va.y);
            a4 += bflo(va.z); a5 += bfhi(va.z);
            a6 += bflo(va.w); a7 += bfhi(va.w);
        }
    }
    // combine the 4 quarters
    a0 += __shfl_xor(a0, 16); a0 += __shfl_xor(a0, 32);
    a1 += __shfl_xor(a1, 16); a1 += __shfl_xor(a1, 32);
    a2 += __shfl_xor(a2, 16); a2 += __shfl_xor(a2, 32);
    a3 += __shfl_xor(a3, 16); a3 += __shfl_xor(a3, 32);
    a4 += __shfl_xor(a4, 16); a4 += __shfl_xor(a4, 32);
    a5 += __shfl_xor(a5, 16); a5 += __shfl_xor(a5, 32);
    a6 += __shfl_xor(a6, 16); a6 += __shfl_xor(a6, 32);
    a7 += __shfl_xor(a7, 16); a7 += __shfl_xor(a7, 32);

    float inv = 1.0f / fmaxf((float)cnt, 1.0f);
    if (q == 0) {
        uint4 o;
        o.x = pkbf(inv * a0, inv * a1);
        o.y = pkbf(inv * a2, inv * a3);
        o.z = pkbf(inv * a4, inv * a5);
        o.w = pkbf(inv * a6, inv * a7);
        xagg4[gw * 16 + cl] = o;
    }
}

// ---- fused gemm12: h1 = relu([xb|xagg]@Bt1^T + b1) (LDS-local), [out|p2] = h1@Bt2^T + b2
__global__ __launch_bounds__(256) void k_gemm12(const uint4* __restrict__ xb4,
                                                const uint4* __restrict__ xagg4,
                                                const unsigned short* __restrict__ Bt1,
                                                const float* __restrict__ b1,
                                                const unsigned short* __restrict__ Bt2,
                                                const float* __restrict__ b2,
                                                float* __restrict__ out,
                                                unsigned short* __restrict__ p2, int M) {
    __shared__ unsigned short As[64][256];
    unsigned short* lds = &As[0][0];
    const int m0 = blockIdx.x * 64;
    const int tid = threadIdx.x;
    const int w = tid >> 6;
    const int l = tid & 63;
    const int fr = l & 15;
    const int kq = l >> 4;

    for (int p = tid; p < 2048; p += 256) {
        int row = p >> 5, c = p & 31;
        int gr = m0 + row;
        uint4 v = make_uint4(0, 0, 0, 0);
        if (gr < M) v = (c < 16) ? xb4[gr * 16 + c] : xagg4[gr * 16 + (c - 16)];
        *(uint4*)&As[row][(c ^ (row & 7)) * 8] = v;
    }
    __syncthreads();

    f32x4 acc[2][4] = {};
#pragma unroll
    for (int kt = 0; kt < 8; ++kt) {
        bf16x8 bfr[2];
#pragma unroll
        for (int ct = 0; ct < 2; ++ct) {
            int nn = w * 32 + ct * 16 + fr;
            bfr[ct] = *(const bf16x8*)&Bt1[nn * 256 + kt * 32 + kq * 8];
        }
        bf16x8 af[4];
#pragma unroll
        for (int rt = 0; rt < 4; ++rt) {
            int row = rt * 16 + fr;
            int c = (kt * 4 + kq) ^ (row & 7);
            af[rt] = *(bf16x8*)&As[row][c * 8];
        }
#pragma unroll
        for (int ct = 0; ct < 2; ++ct)
#pragma unroll
            for (int rt = 0; rt < 4; ++rt)
                acc[ct][rt] = __builtin_amdgcn_mfma_f32_16x16x32_bf16(af[rt], bfr[ct],
                                                                      acc[ct][rt], 0, 0, 0);
    }
    __syncthreads();  // all phase-A LDS reads complete before overwrite

#pragma unroll
    for (int ct = 0; ct < 2; ++ct) {
        int col = w * 32 + ct * 16 + fr;
        float bv = b1[col];
        int c8 = col >> 3, c7 = col & 7;
#pragma unroll
        for (int rt = 0; rt < 4; ++rt) {
#pragma unroll
            for (int j = 0; j < 4; ++j) {
                int row = rt * 16 + (l >> 4) * 4 + j;
                unsigned short hv = f2bf(fmaxf(acc[ct][rt][j] + bv, 0.f));
                lds[row * 128 + (c8 ^ (row & 7)) * 8 + c7] = hv;
            }
        }
    }
    __syncthreads();

    f32x4 acc2[2][4] = {};
#pragma unroll
    for (int kt = 0; kt < 4; ++kt) {
        bf16x8 bfr[2];
#pragma unroll
        for (int ct = 0; ct < 2; ++ct) {
            int nn = w * 32 + ct * 16 + fr;
            bfr[ct] = *(const bf16x8*)&Bt2[nn * 128 + kt * 32 + kq * 8];
        }
        bf16x8 af[4];
#pragma unroll
        for (int rt = 0; rt < 4; ++rt) {
            int row = rt * 16 + fr;
            int c = (kt * 4 + kq) ^ (row & 7);
            af[rt] = *(bf16x8*)&lds[row * 128 + c * 8];
        }
#pragma unroll
        for (int ct = 0; ct < 2; ++ct)
#pragma unroll
            for (int rt = 0; rt < 4; ++rt)
                acc2[ct][rt] = __builtin_amdgcn_mfma_f32_16x16x32_bf16(af[rt], bfr[ct],
                                                                       acc2[ct][rt], 0, 0, 0);
    }

#pragma unroll
    for (int ct = 0; ct < 2; ++ct) {
        int col = w * 32 + ct * 16 + fr;
        bool isS = col < 64;  // wave-uniform per 16-col tile
        float bv = isS ? b2[col] : 0.f;
#pragma unroll
        for (int rt = 0; rt < 4; ++rt) {
#pragma unroll
            for (int j = 0; j < 4; ++j) {
                int row = m0 + rt * 16 + (l >> 4) * 4 + j;
                if (row < M) {
                    float v = acc2[ct][rt][j];
                    if (isS) out[row * 64 + col] = v + bv;
                    else p2[row * 64 + (col - 64)] = f2bf(v);
                }
            }
        }
    }
}

// ---------------- layer-2 aggregation: out += mean_neigh(p2) (64 ch bf16) ----------
// 8 groups of 8 lanes; each group gathers one 128B row via uint4 (8 rows/instr).
__global__ __launch_bounds__(256) void k_agg2_add(const unsigned int* __restrict__ p,
                                                  float* __restrict__ out,
                                                  const int* __restrict__ row_start,
                                                  const int* __restrict__ deg,
                                                  const unsigned short* __restrict__ csr,
                                                  int n) {
    int gw = (blockIdx.x * 256 + threadIdx.x) >> 6;
    int lane = threadIdx.x & 63;
    if (gw >= n) return;
    int start = row_start[gw];
    int cnt = deg[gw];
    const int g = lane >> 3;
    const int cl = lane & 7;
    float a0 = 0.f, a1 = 0.f, a2 = 0.f, a3 = 0.f, a4 = 0.f, a5 = 0.f, a6 = 0.f, a7 = 0.f;
    int i = 0;
    for (; i + 16 <= cnt; i += 16) {
        int e0 = csr[start + i + g];
        int e1 = csr[start + i + 8 + g];
        uint4 v0 = *(const uint4*)&p[e0 * 32 + cl * 4];
        uint4 v1 = *(const uint4*)&p[e1 * 32 + cl * 4];
        a0 += bflo(v0.x) + bflo(v1.x); a1 += bfhi(v0.x) + bfhi(v1.x);
        a2 += bflo(v0.y) + bflo(v1.y); a3 += bfhi(v0.y) + bfhi(v1.y);
        a4 += bflo(v0.z) + bflo(v1.z); a5 += bfhi(v0.z) + bfhi(v1.z);
        a6 += bflo(v0.w) + bflo(v1.w); a7 += bfhi(v0.w) + bfhi(v1.w);
    }
    for (; i < cnt; i += 8) {
        int nbi = i + g;
        if (nbi < cnt) {
            int ia = csr[start + nbi];
            uint4 va = *(const uint4*)&p[ia * 32 + cl * 4];
            a0 += bflo(va.x); a1 += bfhi(va.x);
            a2 += bflo(va.y); a3 += bfhi(va.y);
            a4 += bflo(va.z); a5 += bfhi(va.z);
            a6 += bflo(va.w); a7 += bfhi(va.w);
        }
    }
    a0 += __shfl_xor(a0, 8); a0 += __shfl_xor(a0, 16); a0 += __shfl_xor(a0, 32);
    a1 += __shfl_xor(a1, 8); a1 += __shfl_xor(a1, 16); a1 += __shfl_xor(a1, 32);
    a2 += __shfl_xor(a2, 8); a2 += __shfl_xor(a2, 16); a2 += __shfl_xor(a2, 32);
    a3 += __shfl_xor(a3, 8); a3 += __shfl_xor(a3, 16); a3 += __shfl_xor(a3, 32);
    a4 += __shfl_xor(a4, 8); a4 += __shfl_xor(a4, 16); a4 += __shfl_xor(a4, 32);
    a5 += __shfl_xor(a5, 8); a5 += __shfl_xor(a5, 16); a5 += __shfl_xor(a5, 32);
    a6 += __shfl_xor(a6, 8); a6 += __shfl_xor(a6, 16); a6 += __shfl_xor(a6, 32);
    a7 += __shfl_xor(a7, 8); a7 += __shfl_xor(a7, 16); a7 += __shfl_xor(a7, 32);
    float inv = 1.0f / fmaxf((float)cnt, 1.0f);
    if (g == 0) {
        float4 oa = *(const float4*)&out[gw * 64 + cl * 8];
        float4 ob = *(const float4*)&out[gw * 64 + cl * 8 + 4];
        oa.x += inv * a0; oa.y += inv * a1; oa.z += inv * a2; oa.w += inv * a3;
        ob.x += inv * a4; ob.y += inv * a5; ob.z += inv * a6; ob.w += inv * a7;
        *(float4*)&out[gw * 64 + cl * 8] = oa;
        *(float4*)&out[gw * 64 + cl * 8 + 4] = ob;
    }
}

extern "C" void kernel_launch(void* const* d_in, const int* in_sizes, int n_in,
                              void* d_out, int out_size, void* d_ws, size_t ws_size,
                              hipStream_t stream) {
    const float* x   = (const float*)d_in[0];
    const int*   src = (const int*)d_in[1];
    const int*   dst = (const int*)d_in[2];
    const float* Ws1 = (const float*)d_in[3];
    const float* Wn1 = (const float*)d_in[4];
    const float* b1  = (const float*)d_in[5];
    const float* Ws2 = (const float*)d_in[6];
    const float* Wn2 = (const float*)d_in[7];
    const float* b2  = (const float*)d_in[8];
    float* out = (float*)d_out;
    const int N = in_sizes[0] / N_CH;  // 50000
    const int E = in_sizes[1];         // 800000

    const int nbh  = (E + 1023) / 1024;    // 782 hist/scatter blocks (1024 edges each)
    const int nbkt = (N + 255) / 256;      // 196 buckets (dst>>8)
    const int htot = nbkt * nbh;           // 153272 table entries
    const int nb2  = (htot + 255) / 256;   // 599 scan blocks
    const int nxq  = N * 16;               // 800000 uint4 cast items
    const int nxb  = (nxq + 255) / 256;    // 3125

    // workspace layout (256B-aligned); ws_size ~268MB, ample
    char* ws = (char*)d_ws;
    int* deg       = (int*)(ws + 0);           // N
    int* row_start = (int*)(ws + 200704);      // N
    int* bsum2     = (int*)(ws + 401408);      // nb2 -> 403968
    unsigned short* csr_src = (unsigned short*)(ws + 403968);  // E u16 -> 2003968
    int* H         = (int*)(ws + 2003968);     // htot -> 2617344
    int* Hs        = (int*)(ws + 2617344);     // htot -> 3230720
    int* buf       = (int*)(ws + 3230720);     // E packed -> 6430720
    unsigned short* xb   = (unsigned short*)(ws + 6430720);   // bf16 [N][128]
    unsigned short* xagg = (unsigned short*)(ws + 19230720);  // bf16 [N][128]
    unsigned short* p2   = (unsigned short*)(ws + 32030720);  // bf16 [N][64]
    unsigned short* Bt1  = (unsigned short*)(ws + 38430720);  // 64KB
    unsigned short* Bt2  = (unsigned short*)(ws + 38496256);  // 32KB

    k_hist<<<nbh, 256, 0, stream>>>(dst, H, E, nbh, nbkt);
    k_reduce<<<nb2, 256, 0, stream>>>(H, bsum2, htot);
    k_scan<<<nb2, 256, 0, stream>>>(H, bsum2, Hs, htot);
    k_scatter<<<nbh, 256, 0, stream>>>(src, dst, Hs, buf, E, nbh, nbkt);
    k_bucketcastw<<<nbkt + 192 + nxb, 256, 0, stream>>>(buf, Hs, csr_src, deg, row_start,
                                                        E, nbh, nbkt, N, x, (uint4*)xb, nxq,
                                                        Ws1, Wn1, Ws2, Wn2, Bt1, Bt2);

    k_aggx<<<(N + 3) / 4, 256, 0, stream>>>((const uint4*)xb, (uint4*)xagg, row_start, deg,
                                            csr_src, N);

    const int gb = (N + 63) / 64;  // 782
    k_gemm12<<<gb, 256, 0, stream>>>((const uint4*)xb, (const uint4*)xagg, Bt1, b1, Bt2, b2,
                                     out, p2, N);
    k_agg2_add<<<(N + 3) / 4, 256, 0, stream>>>((const unsigned int*)p2, out, row_start, deg,
                                                csr_src, N);
}